// Round 1
// baseline (184.211 us; speedup 1.0000x reference)
//
#include <hip/hip_runtime.h>

// Problem constants (from reference):
//   in : [2048, 8, 8, 64] complex (as separate re/im float32 planes)
//   out: [2, 2048, 8, 16, 64] float32  (p=0 real plane, p=1 imag plane)
// For block b (even -> qubit 0, odd -> qubit 5):
//   out[b, d, i]     = S * in[b, d, i ^ m]          (d in 0..7, top; real scale)
//   out[b, d+8, i]   = sigma(i) * K * ((re-im) + (re+im)*i)   (bot)
// where m = 32 (even b) / 1 (odd b); sigma = sign of Z on that qubit;
// S = 2^-0.25, K = 2^-0.75 (from c = e^{i pi/4} * 2^-0.25 = K*(1+i)).

#define TOTAL_VEC (2048 * 8 * 8 * 16)   // float4 count per input plane = 2,097,152
#define P_STRIDE  (2048 * 8 * 16 * 64)  // floats per output re/im plane

__global__ __launch_bounds__(256) void entangle_kernel(
    const float4* __restrict__ in_re,
    const float4* __restrict__ in_im,
    float*        __restrict__ out)
{
    const float S = 0.84089641525371454f;  // 2^-0.25
    const float K = 0.59460355750136051f;  // 2^-0.75

    for (int v = blockIdx.x * blockDim.x + threadIdx.x; v < TOTAL_VEC;
         v += gridDim.x * blockDim.x) {
        float4 a = in_re[v];   // 4 consecutive i of the real part
        float4 b = in_im[v];   // imag part

        int i4    = v & 15;        // float4 index within the 64-wide row
        int rem   = v >> 4;
        int d     = rem & 7;
        rem     >>= 3;
        int blk   = rem & 7;
        int batch = rem >> 3;

        int base = batch * 8192 + blk * 1024;   // float offset in one p-plane
        bool even_blk = (blk & 1) == 0;

        // ---- top half: out[d][i] = S * in[d][i ^ m] ----
        float4 tr, ti;
        int top_off;
        if (even_blk) {
            // m = 32: pure address XOR (low 2 bits untouched -> aligned float4)
            top_off = base + d * 64 + ((i4 * 4) ^ 32);
            tr = make_float4(S * a.x, S * a.y, S * a.z, S * a.w);
            ti = make_float4(S * b.x, S * b.y, S * b.z, S * b.w);
        } else {
            // m = 1: swap lanes within the float4
            top_off = base + d * 64 + i4 * 4;
            tr = make_float4(S * a.y, S * a.x, S * a.w, S * a.z);
            ti = make_float4(S * b.y, S * b.x, S * b.w, S * b.z);
        }
        *reinterpret_cast<float4*>(out + top_off)            = tr;
        *reinterpret_cast<float4*>(out + P_STRIDE + top_off) = ti;

        // ---- bottom half: out[d+8][i] = sigma(i) * K * ((a-b) + (a+b) i) ----
        int bot_off = base + (d + 8) * 64 + i4 * 4;
        float4 br, bi;
        if (even_blk) {
            // sigma = +1 for i < 32, -1 otherwise (uniform across this float4)
            float kk = (i4 < 8) ? K : -K;
            br = make_float4(kk * (a.x - b.x), kk * (a.y - b.y),
                             kk * (a.z - b.z), kk * (a.w - b.w));
            bi = make_float4(kk * (a.x + b.x), kk * (a.y + b.y),
                             kk * (a.z + b.z), kk * (a.w + b.w));
        } else {
            // sigma alternates +,-,+,- (i4*4 is even)
            br = make_float4( K * (a.x - b.x), -K * (a.y - b.y),
                              K * (a.z - b.z), -K * (a.w - b.w));
            bi = make_float4( K * (a.x + b.x), -K * (a.y + b.y),
                              K * (a.z + b.z), -K * (a.w + b.w));
        }
        *reinterpret_cast<float4*>(out + bot_off)            = br;
        *reinterpret_cast<float4*>(out + P_STRIDE + bot_off) = bi;
    }
}

extern "C" void kernel_launch(void* const* d_in, const int* in_sizes, int n_in,
                              void* d_out, int out_size, void* d_ws, size_t ws_size,
                              hipStream_t stream) {
    const float4* in_re = reinterpret_cast<const float4*>(d_in[0]);
    const float4* in_im = reinterpret_cast<const float4*>(d_in[1]);
    float* out = reinterpret_cast<float*>(d_out);

    // Memory-bound: cap grid at ~2048 blocks and grid-stride (Guideline 11).
    dim3 block(256);
    dim3 grid(2048);
    entangle_kernel<<<grid, block, 0, stream>>>(in_re, in_im, out);
}